// Round 17
// baseline (54.079 us; speedup 1.0000x reference)
//
#include <hip/hip_runtime.h>

// AdditiveAttention: B=2,H=8,Q=512,K=512,D=64
//   scores[b,h,q,k] = V_b + sum_d V_w[d]*tanh(q_proj[q,d] + k_proj[k,d])
//
// tanh(x) = 1 - 2/(1+e^{2x});  e^{2(qp+kp)} = eq*gk,
//   eq = exp2(C*qp), gk = exp2(C*kp), C = 2*log2(e)
// term_d = Vw[d]/A_d,  A_d = 1 + eq_d*gk_d;  score = (Vb+sumVw) - 2*sum term_d
// tree8: 1 v_rcp per 8 elements, 3.75 VALU/elem.
//
// R17 channel split (ledger-driven):
//   e -> per-lane LDS b32, 8/group, REUSED across 8 k-bodies (R15-proven,
//        lgkmcnt, tiny traffic)
//   G -> VECTOR loads (address derived from threadIdx -> not provably
//        uniform -> global_load_dwordx4), vmcnt-tracked, L1-resident 8KB
//        tile (R12-proven channel). Different counter than e -> no joint
//        lgkmcnt(0) drain per group (R15's residual stall).
//   Vw -> scalar K$.

#define BHX 16
#define SEQ 512
#define DDIM 64

typedef float f4 __attribute__((ext_vector_type(4)));

// Both projections in one launch. blocks 0..255: query->eq, 256..511: keys->gk.
// (R12-proven, no pins.)
__global__ __launch_bounds__(256) void proj_kernel(
    const float* __restrict__ query, const float* __restrict__ keys,
    const float* __restrict__ Wa_w,  const float* __restrict__ Wa_b,
    const float* __restrict__ Ua_w,  const float* __restrict__ Ua_b,
    float* __restrict__ eq, float* __restrict__ gk)
{
  const int t = threadIdx.x, lane = t & 63, wave = t >> 6;
  const bool is_k = blockIdx.x >= 256;
  const float* __restrict__ X  = is_k ? keys : query;
  const float* __restrict__ W  = is_k ? Ua_w : Wa_w;
  const float* __restrict__ Bv = is_k ? Ua_b : Wa_b;
  float* __restrict__ out      = is_k ? gk : eq;
  const int row0 = (blockIdx.x & 255) * 32;

  float w[64];
  const float4* W4 = (const float4*)(W + lane * DDIM);
#pragma unroll
  for (int i = 0; i < 16; ++i) {
    float4 v = W4[i];
    w[4*i] = v.x; w[4*i+1] = v.y; w[4*i+2] = v.z; w[4*i+3] = v.w;
  }

  const float C = 2.885390081777926815f;          // 2*log2(e)
  const float b = Bv[lane];

#pragma unroll 1
  for (int i = 0; i < 8; ++i) {
    const int r   = row0 + wave * 8 + i;
    const int off = __builtin_amdgcn_readfirstlane(r * DDIM);
    const float* xr = X + off;                    // wave-uniform -> s_load
    float a0 = 0, a1 = 0, a2 = 0, a3 = 0;
#pragma unroll
    for (int e = 0; e < 64; e += 4) {
      a0 = __builtin_fmaf(xr[e],     w[e],     a0);
      a1 = __builtin_fmaf(xr[e + 1], w[e + 1], a1);
      a2 = __builtin_fmaf(xr[e + 2], w[e + 2], a2);
      a3 = __builtin_fmaf(xr[e + 3], w[e + 3], a3);
    }
    float p = ((a0 + a1) + (a2 + a3)) + b;
    out[(size_t)r * DDIM + lane] = __builtin_amdgcn_exp2f(C * p);
  }
}

// Grid (16,8,16)=2048 blocks. Block tile: 64 q x 32 k.
// Wave w: k in [8w, 8w+8), lane = q. LDS 16.6KB (eql, reused for out-staging).
__global__ __launch_bounds__(256, 4) void score_kernel(
    const float* __restrict__ eq,   // [BH*512][64]
    const float* __restrict__ gk,   // [BH*512][64]
    const float* __restrict__ Vw,   // [64]
    const float* __restrict__ Vb,   // [1]
    float* __restrict__ out)        // [BH,512,512]
{
  __shared__ float eql[DDIM][65];   // [d][q] transposed, +1 pad (16.6 KB)

  const int bh   = blockIdx.z;
  const int q0   = blockIdx.y * 64;
  const int k0   = blockIdx.x * 32;
  const int t    = threadIdx.x;
  const int lane = t & 63;          // = q within tile
  const int wave = t >> 6;          // k-strip: k in [8*wave, 8*wave+8)

  // ---- stage eq tile TRANSPOSED: [d][q] (R15-proven, ~2-way banks) ----
  {
    const float* eqb = eq + (size_t)(bh * SEQ + q0) * DDIM;
#pragma unroll
    for (int h = 0; h < 4; ++h) {
      const int idx = t + 256 * h;        // 0..1023 quads
      const int q   = idx >> 4;
      const int d0  = (idx & 15) * 4;
      const f4 v = *(const f4*)(eqb + q * DDIM + d0);
      eql[d0][q]     = v.x;
      eql[d0 + 1][q] = v.y;
      eql[d0 + 2][q] = v.z;
      eql[d0 + 3][q] = v.w;
    }
  }

  // acc0 = V_b + sum_d V_w[d]  (uniform scalar)
  float acc0 = Vb[0];
#pragma unroll
  for (int d = 0; d < 64; ++d) acc0 += Vw[d];

  __syncthreads();

  float acc[8] = {0.f, 0.f, 0.f, 0.f, 0.f, 0.f, 0.f, 0.f};
  // G base: derived from threadIdx (NOT readfirstlane) -> compiler's
  // divergence analysis keeps these as VECTOR loads (vmcnt channel).
  const float* Gw = gk + (size_t)(bh * SEQ + k0 + wave * 8) * DDIM;

#pragma unroll 1
  for (int g = 0; g < 8; ++g) {           // d-groups of 8
    // lane's 8 e-values (its q-row): conflict-free b32, reused across 8 k.
    float e_[8];
#pragma unroll
    for (int j = 0; j < 8; ++j) e_[j] = eql[8 * g + j][lane];
    float vw[8];
#pragma unroll
    for (int j = 0; j < 8; ++j) vw[j] = Vw[8 * g + j];

    // G for this group: 16 vector dwordx4 loads (uniform addr -> 1 L1
    // access each; tile is L1-resident after group 0). vmcnt-tracked.
    f4 Gc[16];
#pragma unroll
    for (int kk = 0; kk < 8; ++kk) {
      Gc[2 * kk]     = *(const f4*)(Gw + kk * DDIM + 8 * g);
      Gc[2 * kk + 1] = *(const f4*)(Gw + kk * DDIM + 8 * g + 4);
    }

#pragma unroll
    for (int kk = 0; kk < 8; ++kk) {      // register-only bodies; acc static
      float A[8];
      A[0] = __builtin_fmaf(e_[0], Gc[2*kk].x,     1.0f);
      A[1] = __builtin_fmaf(e_[1], Gc[2*kk].y,     1.0f);
      A[2] = __builtin_fmaf(e_[2], Gc[2*kk].z,     1.0f);
      A[3] = __builtin_fmaf(e_[3], Gc[2*kk].w,     1.0f);
      A[4] = __builtin_fmaf(e_[4], Gc[2*kk + 1].x, 1.0f);
      A[5] = __builtin_fmaf(e_[5], Gc[2*kk + 1].y, 1.0f);
      A[6] = __builtin_fmaf(e_[6], Gc[2*kk + 1].z, 1.0f);
      A[7] = __builtin_fmaf(e_[7], Gc[2*kk + 1].w, 1.0f);
      // tree8: sum_j vw[j]/A[j] = num/P, 1 rcp
      const float n01 = __builtin_fmaf(vw[1], A[0], vw[0] * A[1]);
      const float n23 = __builtin_fmaf(vw[3], A[2], vw[2] * A[3]);
      const float n45 = __builtin_fmaf(vw[5], A[4], vw[4] * A[5]);
      const float n67 = __builtin_fmaf(vw[7], A[6], vw[6] * A[7]);
      const float P01 = A[0] * A[1], P23 = A[2] * A[3];
      const float P45 = A[4] * A[5], P67 = A[6] * A[7];
      const float n0123 = __builtin_fmaf(n23, P01, n01 * P23);
      const float n4567 = __builtin_fmaf(n67, P45, n45 * P67);
      const float P0123 = P01 * P23, P4567 = P45 * P67;
      const float num = __builtin_fmaf(n4567, P0123, n0123 * P4567);
      const float P   = P0123 * P4567;    // product of 8 A's >= 1: safe
      acc[kk] = __builtin_fmaf(num, __builtin_amdgcn_rcpf(P), acc[kk]);
    }
  }

  // ---- transpose results through (reused) LDS for coalesced stores ----
  __syncthreads();                        // all eql reads complete
  float* lo = &eql[0][0];                 // reuse as [64 q][33 k]
#pragma unroll
  for (int kk = 0; kk < 8; ++kk)          // bank (q + k)%32 -> 2/bank
    lo[lane * 33 + wave * 8 + kk] = __builtin_fmaf(-2.f, acc[kk], acc0);
  __syncthreads();

  {
    const int row = t >> 2;               // q row 0..63
    const int c0  = (t & 3) * 8;          // k col start
    const float* src = lo + row * 33 + c0;
    f4 v0, v1;
    v0.x = src[0]; v0.y = src[1]; v0.z = src[2]; v0.w = src[3];
    v1.x = src[4]; v1.y = src[5]; v1.z = src[6]; v1.w = src[7];
    float* dst = out + (size_t)(bh * SEQ + q0 + row) * SEQ + k0 + c0;
    *(f4*)(dst)     = v0;
    *(f4*)(dst + 4) = v1;
  }
}

extern "C" void kernel_launch(void* const* d_in, const int* in_sizes, int n_in,
                              void* d_out, int out_size, void* d_ws, size_t ws_size,
                              hipStream_t stream) {
  const float* query = (const float*)d_in[0];  // [2,8,512,64]
  const float* keys  = (const float*)d_in[1];  // [2,8,512,64]
  const float* Wa_w  = (const float*)d_in[2];  // [64,64]
  const float* Wa_b  = (const float*)d_in[3];  // [64]
  const float* Ua_w  = (const float*)d_in[4];  // [64,64]
  const float* Ua_b  = (const float*)d_in[5];  // [64]
  const float* V_w   = (const float*)d_in[6];  // [64]
  const float* V_b   = (const float*)d_in[7];  // [1]
  float* out = (float*)d_out;

  const int R = BHX * SEQ;                 // 8192 rows each side
  float* eqw = (float*)d_ws;               // 2 MiB
  float* gkw = eqw + (size_t)R * DDIM;     // 2 MiB

  proj_kernel<<<512, 256, 0, stream>>>(query, keys, Wa_w, Wa_b,
                                       Ua_w, Ua_b, eqw, gkw);

  dim3 grid(SEQ / 32, SEQ / 64, BHX);      // (16,8,16) = 2048 blocks
  score_kernel<<<grid, 256, 0, stream>>>(eqw, gkw, V_w, V_b, out);
}

// Round 18
// 40.727 us; speedup vs baseline: 1.3278x; 1.3278x over previous
//
#include <hip/hip_runtime.h>

// AdditiveAttention: B=2,H=8,Q=512,K=512,D=64
//   scores[b,h,q,k] = V_b + sum_d V_w[d]*tanh(q_proj[q,d] + k_proj[k,d])
//
// tanh(x) = 1 - 2/(1+e^{2x});  e^{2(qp+kp)} = eq*gk,
//   eq = exp2(C*qp), gk = exp2(C*kp), C = 2*log2(e)
// term_d = Vw[d]/A_d,  A_d = 1 + eq_d*gk_d;  score = (Vb+sumVw) - 2*sum term_d
// tree8: 1 v_rcp per 8 elements, 3.875 VALU/elem.
//
// R18 = R15 (best, 40.4us) + __launch_bounds__(256,8): the pipe-split design
//   e  -> per-lane LDS b32, 8/group, reused across 8 k-bodies (lane = q)
//   G  -> per-group batched uniform s_load (8 x dwordx8 -> SGPRs), ONE drain
//   Vw -> scalar K$
// with VGPR forced <= 64 so the 16.6KB-LDS-permitted 8 blocks/CU actually
// yields 8 waves/SIMD to cover the per-group lgkmcnt drains (SMEM returns
// are out-of-order -> compiler must fully drain; hiding requires waves).

#define BHX 16
#define SEQ 512
#define DDIM 64

typedef float f4 __attribute__((ext_vector_type(4)));

// Both projections in one launch. blocks 0..255: query->eq, 256..511: keys->gk.
// (R12-proven, no pins.)
__global__ __launch_bounds__(256) void proj_kernel(
    const float* __restrict__ query, const float* __restrict__ keys,
    const float* __restrict__ Wa_w,  const float* __restrict__ Wa_b,
    const float* __restrict__ Ua_w,  const float* __restrict__ Ua_b,
    float* __restrict__ eq, float* __restrict__ gk)
{
  const int t = threadIdx.x, lane = t & 63, wave = t >> 6;
  const bool is_k = blockIdx.x >= 256;
  const float* __restrict__ X  = is_k ? keys : query;
  const float* __restrict__ W  = is_k ? Ua_w : Wa_w;
  const float* __restrict__ Bv = is_k ? Ua_b : Wa_b;
  float* __restrict__ out      = is_k ? gk : eq;
  const int row0 = (blockIdx.x & 255) * 32;

  float w[64];
  const float4* W4 = (const float4*)(W + lane * DDIM);
#pragma unroll
  for (int i = 0; i < 16; ++i) {
    float4 v = W4[i];
    w[4*i] = v.x; w[4*i+1] = v.y; w[4*i+2] = v.z; w[4*i+3] = v.w;
  }

  const float C = 2.885390081777926815f;          // 2*log2(e)
  const float b = Bv[lane];

#pragma unroll 1
  for (int i = 0; i < 8; ++i) {
    const int r   = row0 + wave * 8 + i;
    const int off = __builtin_amdgcn_readfirstlane(r * DDIM);
    const float* xr = X + off;                    // wave-uniform -> s_load
    float a0 = 0, a1 = 0, a2 = 0, a3 = 0;
#pragma unroll
    for (int e = 0; e < 64; e += 4) {
      a0 = __builtin_fmaf(xr[e],     w[e],     a0);
      a1 = __builtin_fmaf(xr[e + 1], w[e + 1], a1);
      a2 = __builtin_fmaf(xr[e + 2], w[e + 2], a2);
      a3 = __builtin_fmaf(xr[e + 3], w[e + 3], a3);
    }
    float p = ((a0 + a1) + (a2 + a3)) + b;
    out[(size_t)r * DDIM + lane] = __builtin_amdgcn_exp2f(C * p);
  }
}

// Grid (16,8,16)=2048 blocks = 8 blocks/CU. Block tile: 64 q x 32 k.
// Wave w: k in [8w, 8w+8), lane = q. LDS 16.6KB (eql, reused for out-staging).
__global__ __launch_bounds__(256, 8) void score_kernel(
    const float* __restrict__ eq,   // [BH*512][64]
    const float* __restrict__ gk,   // [BH*512][64]
    const float* __restrict__ Vw,   // [64]
    const float* __restrict__ Vb,   // [1]
    float* __restrict__ out)        // [BH,512,512]
{
  __shared__ float eql[DDIM][65];   // [d][q] transposed, +1 pad (16.6 KB)

  const int bh   = blockIdx.z;
  const int q0   = blockIdx.y * 64;
  const int k0   = blockIdx.x * 32;
  const int t    = threadIdx.x;
  const int lane = t & 63;          // = q within tile
  const int wave = t >> 6;          // k-strip: k in [8*wave, 8*wave+8)

  // ---- stage eq tile TRANSPOSED: [d][q] ----
  {
    const float* eqb = eq + (size_t)(bh * SEQ + q0) * DDIM;
#pragma unroll
    for (int h = 0; h < 4; ++h) {
      const int idx = t + 256 * h;        // 0..1023 quads
      const int q   = idx >> 4;
      const int d0  = (idx & 15) * 4;
      const f4 v = *(const f4*)(eqb + q * DDIM + d0);
      eql[d0][q]     = v.x;
      eql[d0 + 1][q] = v.y;
      eql[d0 + 2][q] = v.z;
      eql[d0 + 3][q] = v.w;
    }
  }

  // acc0 = V_b + sum_d V_w[d]  (uniform scalar)
  float acc0 = Vb[0];
#pragma unroll
  for (int d = 0; d < 64; ++d) acc0 += Vw[d];

  __syncthreads();

  float acc[8] = {0.f, 0.f, 0.f, 0.f, 0.f, 0.f, 0.f, 0.f};
  // wave-uniform G base for this wave's 8 k rows (readfirstlane -> scalar)
  const int goff = __builtin_amdgcn_readfirstlane(
      (bh * SEQ + k0) * DDIM + (threadIdx.x >> 6) * 8 * DDIM);
  const float* Gb = gk + goff;

#pragma unroll 1
  for (int g = 0; g < 8; ++g) {           // d-groups of 8
    // lane's 8 e-values (its q-row): conflict-free b32, reused across 8 k.
    float e_[8];
#pragma unroll
    for (int j = 0; j < 8; ++j) e_[j] = eql[8 * g + j][lane];
    float vw[8];
#pragma unroll
    for (int j = 0; j < 8; ++j) vw[j] = Vw[8 * g + j];

    // ---- batched G prefetch: ALL 64 floats for this group, one drain.
    // Uniform base + affine offsets -> 8 contiguous s_load_dwordx8 -> SGPRs.
    float Gc[64];
#pragma unroll
    for (int kk = 0; kk < 8; ++kk)
#pragma unroll
      for (int j = 0; j < 8; ++j)
        Gc[kk * 8 + j] = Gb[kk * DDIM + 8 * g + j];

#pragma unroll
    for (int kk = 0; kk < 8; ++kk) {      // register-only bodies; acc static
      float A[8];
#pragma unroll
      for (int j = 0; j < 8; ++j)
        A[j] = __builtin_fmaf(e_[j], Gc[kk * 8 + j], 1.0f);
      // tree8: sum_j vw[j]/A[j] = num/P, 1 rcp
      const float n01 = __builtin_fmaf(vw[1], A[0], vw[0] * A[1]);
      const float n23 = __builtin_fmaf(vw[3], A[2], vw[2] * A[3]);
      const float n45 = __builtin_fmaf(vw[5], A[4], vw[4] * A[5]);
      const float n67 = __builtin_fmaf(vw[7], A[6], vw[6] * A[7]);
      const float P01 = A[0] * A[1], P23 = A[2] * A[3];
      const float P45 = A[4] * A[5], P67 = A[6] * A[7];
      const float n0123 = __builtin_fmaf(n23, P01, n01 * P23);
      const float n4567 = __builtin_fmaf(n67, P45, n45 * P67);
      const float P0123 = P01 * P23, P4567 = P45 * P67;
      const float num = __builtin_fmaf(n4567, P0123, n0123 * P4567);
      const float P   = P0123 * P4567;    // product of 8 A's >= 1: safe
      acc[kk] = __builtin_fmaf(num, __builtin_amdgcn_rcpf(P), acc[kk]);
    }
  }

  // ---- transpose results through (reused) LDS for coalesced stores ----
  __syncthreads();                        // all eql reads complete
  float* lo = &eql[0][0];                 // reuse as [64 q][33 k]
#pragma unroll
  for (int kk = 0; kk < 8; ++kk)          // bank (q + k)%32 -> 2/bank
    lo[lane * 33 + wave * 8 + kk] = __builtin_fmaf(-2.f, acc[kk], acc0);
  __syncthreads();

  {
    const int row = t >> 2;               // q row 0..63
    const int c0  = (t & 3) * 8;          // k col start
    const float* src = lo + row * 33 + c0;
    f4 v0, v1;
    v0.x = src[0]; v0.y = src[1]; v0.z = src[2]; v0.w = src[3];
    v1.x = src[4]; v1.y = src[5]; v1.z = src[6]; v1.w = src[7];
    float* dst = out + (size_t)(bh * SEQ + q0 + row) * SEQ + k0 + c0;
    *(f4*)(dst)     = v0;
    *(f4*)(dst + 4) = v1;
  }
}

extern "C" void kernel_launch(void* const* d_in, const int* in_sizes, int n_in,
                              void* d_out, int out_size, void* d_ws, size_t ws_size,
                              hipStream_t stream) {
  const float* query = (const float*)d_in[0];  // [2,8,512,64]
  const float* keys  = (const float*)d_in[1];  // [2,8,512,64]
  const float* Wa_w  = (const float*)d_in[2];  // [64,64]
  const float* Wa_b  = (const float*)d_in[3];  // [64]
  const float* Ua_w  = (const float*)d_in[4];  // [64,64]
  const float* Ua_b  = (const float*)d_in[5];  // [64]
  const float* V_w   = (const float*)d_in[6];  // [64]
  const float* V_b   = (const float*)d_in[7];  // [1]
  float* out = (float*)d_out;

  const int R = BHX * SEQ;                 // 8192 rows each side
  float* eqw = (float*)d_ws;               // 2 MiB
  float* gkw = eqw + (size_t)R * DDIM;     // 2 MiB

  proj_kernel<<<512, 256, 0, stream>>>(query, keys, Wa_w, Wa_b,
                                       Ua_w, Ua_b, eqw, gkw);

  dim3 grid(SEQ / 32, SEQ / 64, BHX);      // (16,8,16) = 2048 blocks
  score_kernel<<<grid, 256, 0, stream>>>(eqw, gkw, V_w, V_b, out);
}